// Round 7
// baseline (274.493 us; speedup 1.0000x reference)
//
#include <hip/hip_runtime.h>
#include <math.h>

#define NB    2
#define NQ    900
#define NQP   960
#define NKV   4096
#define DIMM  256
#define NHEAD 8
#define HD    32
#define RPEH  512
#define GRID  64
#define SPLIT 4
#define KVSEG 1024
#define NT    16

typedef short short8 __attribute__((ext_vector_type(8)));
typedef float f32x4 __attribute__((ext_vector_type(4)));
typedef float f32x16 __attribute__((ext_vector_type(16)));
typedef unsigned uint2v __attribute__((ext_vector_type(2)));
typedef unsigned short u16;
typedef unsigned short u16x4 __attribute__((ext_vector_type(4)));

__device__ inline u16 f2bf(float f) {
    unsigned u = __builtin_bit_cast(unsigned, f);
    u += 0x7fff + ((u >> 16) & 1);
    return (u16)(u >> 16);
}
__device__ inline unsigned packbf2(float a, float b) {
    unsigned ua = __builtin_bit_cast(unsigned, a);
    ua += 0x7fff + ((ua >> 16) & 1);
    unsigned ub = __builtin_bit_cast(unsigned, b);
    ub += 0x7fff + ((ub >> 16) & 1);
    return (ua >> 16) | (ub & 0xffff0000u);
}

// ---------------------------------------------------------------------------
// fp32 -> bf16 conversion prepass (hs, kv, q_w, k_w, v_w), one launch.
// ---------------------------------------------------------------------------
#define HS4  115200   // 1800*256/4
#define KV4  524288   // 8192*256/4
#define W4   16384    // 256*256/4
__global__ __launch_bounds__(256) void conv_bf16(
    const float* __restrict__ hs, const float* __restrict__ kv,
    const float* __restrict__ qw, const float* __restrict__ kw,
    const float* __restrict__ vw,
    u16* __restrict__ hsbf, u16* __restrict__ kvbf,
    u16* __restrict__ qwbf, u16* __restrict__ kwbf, u16* __restrict__ vwbf)
{
    const int total = HS4 + KV4 + 3 * W4;
    for (int g = blockIdx.x * 256 + threadIdx.x; g < total; g += gridDim.x * 256) {
        const float* s; u16* d; int off;
        if (g < HS4)                       { s = hs; d = hsbf; off = g; }
        else if (g < HS4 + KV4)            { s = kv; d = kvbf; off = g - HS4; }
        else if (g < HS4 + KV4 + W4)       { s = qw; d = qwbf; off = g - HS4 - KV4; }
        else if (g < HS4 + KV4 + 2 * W4)   { s = kw; d = kwbf; off = g - HS4 - KV4 - W4; }
        else                               { s = vw; d = vwbf; off = g - HS4 - KV4 - 2 * W4; }
        f32x4 v = *(const f32x4*)(s + (size_t)off * 4);
        *(u16x4*)(d + (size_t)off * 4) =
            (u16x4){f2bf(v[0]), f2bf(v[1]), f2bf(v[2]), f2bf(v[3])};
    }
}

// ---------------------------------------------------------------------------
// Pack RPE weights, 16-float records: wpkg[m][r][16] =
// {a, b, bias, a+b, w2t[0..7], 0,0,0,0} -> one s_load_dwordx16 per record.
// ---------------------------------------------------------------------------
__global__ __launch_bounds__(256) void rpe_pack(
    const float* __restrict__ w1x, const float* __restrict__ b1x,
    const float* __restrict__ w2x,
    const float* __restrict__ w1y, const float* __restrict__ b1y,
    const float* __restrict__ w2y,
    float* __restrict__ wpkg)
{
    int i = blockIdx.x * 256 + threadIdx.x;
    if (i >= 2 * RPEH * 16) return;
    int m = i >> 13;
    int r = (i >> 4) & (RPEH - 1);
    int j = i & 15;
    const float* w1 = m ? w1y : w1x;
    const float* b1 = m ? b1y : b1x;
    const float* w2 = m ? w2y : w2x;
    float v;
    if (j == 0)       v = w1[r * 2];
    else if (j == 1)  v = w1[r * 2 + 1];
    else if (j == 2)  v = b1[r];
    else if (j == 3)  v = w1[r * 2] + w1[r * 2 + 1];
    else if (j < 12)  v = w2[(j - 4) * RPEH + r];
    else              v = 0.f;
    wpkg[i] = v;
}

// ---------------------------------------------------------------------------
// bf16 MFMA projection GEMM (unchanged, verified).
// ---------------------------------------------------------------------------
__global__ __launch_bounds__(256) void proj_mfma(
    const u16* __restrict__ A,
    const u16* __restrict__ W0, const float* __restrict__ B0,
    const u16* __restrict__ W1, const float* __restrict__ B1,
    u16* __restrict__ outRow, u16* __restrict__ outVt,
    int M, float scale)
{
    __shared__ u16 Abuf[2][4096];
    __shared__ u16 Bbuf[2][4096];

    const u16* W = W0; const float* bias = B0; bool vt = false;
    if (blockIdx.z == 1) { W = W1; bias = B1; vt = true; }

    const int t    = threadIdx.x;
    const int lane = t & 63;
    const int w    = t >> 6;
    const int wm   = w >> 1, wn = w & 1;
    const int m0   = blockIdx.x * 128;
    const int n0   = blockIdx.y * 128;

    const int r0 = t >> 2, c0 = t & 3;
    const int r1 = r0 + 64;
    const int s0 = r0 * 4 + (c0 ^ (r0 & 3));
    const int s1 = r1 * 4 + (c0 ^ (r1 & 3));
    const u16* Arow0 = A + (size_t)(m0 + r0) * DIMM + c0 * 8;
    const u16* Arow1 = A + (size_t)(m0 + r1) * DIMM + c0 * 8;
    const u16* Wrow0 = W + (size_t)(n0 + r0) * DIMM + c0 * 8;
    const u16* Wrow1 = W + (size_t)(n0 + r1) * DIMM + c0 * 8;

    const int fr = lane & 15, fkc = lane >> 4;
    int aslot[4], bslot[4];
    #pragma unroll
    for (int f = 0; f < 4; ++f) {
        int ar = wm * 64 + f * 16 + fr;
        int br = wn * 64 + f * 16 + fr;
        aslot[f] = ar * 4 + (fkc ^ (ar & 3));
        bslot[f] = br * 4 + (fkc ^ (br & 3));
    }
    float bv[4];
    #pragma unroll
    for (int f = 0; f < 4; ++f) bv[f] = bias[n0 + wn * 64 + f * 16 + fr];

    f32x4 acc[4][4] = {};

    {
        short8 a0 = *(const short8*)(Arow0);
        short8 a1 = *(const short8*)(Arow1);
        short8 b0 = *(const short8*)(Wrow0);
        short8 b1 = *(const short8*)(Wrow1);
        *(short8*)&Abuf[0][s0 * 8] = a0;
        *(short8*)&Abuf[0][s1 * 8] = a1;
        *(short8*)&Bbuf[0][s0 * 8] = b0;
        *(short8*)&Bbuf[0][s1 * 8] = b1;
    }
    __syncthreads();

    int cur = 0;
    for (int kt = 0; kt < 8; ++kt) {
        short8 na0, na1, nb0, nb1;
        if (kt < 7) {
            int ko = (kt + 1) * 32;
            na0 = *(const short8*)(Arow0 + ko);
            na1 = *(const short8*)(Arow1 + ko);
            nb0 = *(const short8*)(Wrow0 + ko);
            nb1 = *(const short8*)(Wrow1 + ko);
        }
        short8 af[4], bf[4];
        #pragma unroll
        for (int f = 0; f < 4; ++f) {
            af[f] = *(const short8*)&Abuf[cur][aslot[f] * 8];
            bf[f] = *(const short8*)&Bbuf[cur][bslot[f] * 8];
        }
        #pragma unroll
        for (int i = 0; i < 4; ++i)
            #pragma unroll
            for (int j = 0; j < 4; ++j)
                acc[i][j] = __builtin_amdgcn_mfma_f32_16x16x32_bf16(af[i], bf[j], acc[i][j], 0, 0, 0);
        if (kt < 7) {
            *(short8*)&Abuf[cur ^ 1][s0 * 8] = na0;
            *(short8*)&Abuf[cur ^ 1][s1 * 8] = na1;
            *(short8*)&Bbuf[cur ^ 1][s0 * 8] = nb0;
            *(short8*)&Bbuf[cur ^ 1][s1 * 8] = nb1;
        }
        __syncthreads();
        cur ^= 1;
    }

    #pragma unroll
    for (int i = 0; i < 4; ++i) {
        int mbase = m0 + wm * 64 + i * 16 + 4 * fkc;
        #pragma unroll
        for (int j = 0; j < 4; ++j) {
            int n = n0 + wn * 64 + j * 16 + fr;
            #pragma unroll
            for (int r = 0; r < 4; ++r) {
                int gm = mbase + r;
                if (gm < M) {
                    float v = (acc[i][j][r] + bv[j]) * scale;
                    if (!vt) {
                        outRow[(size_t)gm * DIMM + n] = f2bf(v);
                    } else {
                        int bb = gm >> 12, kvi = gm & 4095;
                        int hh = n >> 5, dd = n & 31;
                        outVt[(size_t)((bb * NHEAD + hh) * HD + dd) * NKV + kvi] = f2bf(v);
                    }
                }
            }
        }
    }
}

// ---------------------------------------------------------------------------
// RPE MLPs, scalar-load weights. Block = 4 waves = 4 bq (same m).
// Weight addresses depend ONLY on blockIdx + loop counter (+ readfirstlane
// hedge) -> provably wave-uniform -> s_load_dwordx16 path, zero LDS.
// Each wave iterates all 512 hidden units for its own bq.
// ---------------------------------------------------------------------------
__global__ __launch_bounds__(256) void rpe_kernel(
    const float* __restrict__ ref_pts,
    const float* __restrict__ wpkg,
    float* __restrict__ rpex, float* __restrict__ rpey)
{
    const int t    = threadIdx.x;
    const int lane = t & 63;
    const int wv   = t >> 6;
    const int m    = blockIdx.x & 1;
    const int bq   = (blockIdx.x >> 1) * 4 + wv;
    const float p  = (lane + 0.5f) * 16.f;

    const float* q = ref_pts + (size_t)bq * 4;
    const float c = m ? q[1] : q[0];
    const float s = m ? q[3] : q[2];
    const float lo = (c - s * 0.5f) * 1024.f;
    const float hi = (c + s * 0.5f) * 1024.f;

    // base pointer: blockIdx-only + readfirstlane hedge (explicit uniformity)
    unsigned long long ap = (unsigned long long)(wpkg + (size_t)m * RPEH * 16);
    unsigned alo = __builtin_amdgcn_readfirstlane((unsigned)ap);
    unsigned ahi = __builtin_amdgcn_readfirstlane((unsigned)(ap >> 32));
    const f32x16* wp = (const f32x16*)((((unsigned long long)ahi) << 32) | alo);

    float2 acc[4] = {};
    #pragma unroll 4
    for (int r = 0; r < RPEH; ++r) {
        f32x16 wr = wp[r];
        float al  = fmaf(wr[0], lo, fmaf(wr[1], hi, wr[2]));
        float hid = fmaxf(fmaf(-wr[3], p, al), 0.f);
        acc[0].x = fmaf(wr[4],  hid, acc[0].x);
        acc[0].y = fmaf(wr[5],  hid, acc[0].y);
        acc[1].x = fmaf(wr[6],  hid, acc[1].x);
        acc[1].y = fmaf(wr[7],  hid, acc[1].y);
        acc[2].x = fmaf(wr[8],  hid, acc[2].x);
        acc[2].y = fmaf(wr[9],  hid, acc[2].y);
        acc[3].x = fmaf(wr[10], hid, acc[3].x);
        acc[3].y = fmaf(wr[11], hid, acc[3].y);
    }

    float* outp = m ? rpey : rpex;
    size_t base = (size_t)bq * (NHEAD * GRID) + lane;
    #pragma unroll
    for (int j = 0; j < 4; ++j) {
        outp[base + (2 * j) * GRID]     = acc[j].x;
        outp[base + (2 * j + 1) * GRID] = acc[j].y;
    }
}

// ---------------------------------------------------------------------------
// MFMA attention, KV-split flash-decode (unchanged, verified).
// ---------------------------------------------------------------------------
__global__ __launch_bounds__(256) void attn_mfma(
    const u16* __restrict__ Qbf, const u16* __restrict__ Kbf,
    const u16* __restrict__ Vt,
    const float* __restrict__ RX, const float* __restrict__ RY,
    const int* __restrict__ mask,
    float* __restrict__ pctx, float2* __restrict__ pml)
{
    __shared__ short8 kbuf[2][4][64];
    __shared__ short8 vbuf[2][4][64];
    __shared__ unsigned pbuf[4][2][64][4];
    __shared__ float ry_s[16][68];
    __shared__ float mbuf[2][64];

    const int tid  = threadIdx.x;
    const int lane = tid & 63;
    const int w    = tid >> 6;
    const int q15  = lane & 15;
    const int g    = lane >> 4;
    const int qt = blockIdx.x, h = blockIdx.y;
    const int b  = blockIdx.z >> 2;
    const int sp = blockIdx.z & 3;
    const int q0 = qt * 64;
    const int wq = w * 16 + q15;
    const int gq = q0 + wq;
    const bool qok = gq < NQ;
    const int kv0g = sp * KVSEG;

    float rxr[16];
    {
        const float* rxrow = RX + (size_t)(b * NQ + (qok ? gq : 0)) * (NHEAD * GRID) + h * GRID;
        #pragma unroll
        for (int kt = 0; kt < 4; ++kt)
            #pragma unroll
            for (int r = 0; r < 4; ++r)
                rxr[kt * 4 + r] = qok ? rxrow[16 * kt + 4 * g + r] : 0.f;
    }
    for (int idx = tid; idx < 16 * 64; idx += 256) {
        int y = idx & 15, q = idx >> 4;
        int gq2 = q0 + q;
        ry_s[y][q] = (gq2 < NQ)
            ? RY[(size_t)(b * NQ + gq2) * (NHEAD * GRID) + h * GRID + sp * 16 + y] : 0.f;
    }

    short8 qf = *(const short8*)(Qbf + ((size_t)(b * NQ + gq)) * DIMM + h * HD + 8 * g);

    const int sr = tid >> 2, sc = tid & 3;
    const int vd = tid >> 3, vc = tid & 7;
    const size_t kbase = ((size_t)(b * NKV + kv0g + sr)) * DIMM + h * HD + 8 * sc;
    const size_t vbase = ((size_t)((b * NHEAD + h) * HD + vd)) * NKV + kv0g + 8 * vc;

    kbuf[0][sr >> 4][(sr & 15) + 16 * sc] = *(const short8*)(Kbf + kbase);
    vbuf[0][(vc >> 2) * 2 + (vd >> 4)][16 * (vc & 3) + (vd & 15)] = *(const short8*)(Vt + vbase);
    if (tid < 64) mbuf[0][tid] = -100.f * (float)mask[b * NKV + kv0g + tid];
    __syncthreads();

    f32x4 cacc0 = {0.f, 0.f, 0.f, 0.f};
    f32x4 cacc1 = {0.f, 0.f, 0.f, 0.f};
    float m_run = -1e30f, l_run = 0.f;
    int cur = 0;

    for (int t = 0; t < NT; ++t) {
        short8 rk = {}, rv = {};
        float rm = 0.f;
        if (t < NT - 1) {
            size_t kvn = (size_t)(t + 1) * 64;
            rk = *(const short8*)(Kbf + kbase + kvn * DIMM);
            rv = *(const short8*)(Vt + vbase + kvn);
            if (tid < 64) rm = -100.f * (float)mask[b * NKV + kv0g + kvn + tid];
        }

        f32x4 zero = {0.f, 0.f, 0.f, 0.f};
        f32x4 s[4];
        __builtin_amdgcn_s_setprio(1);
        #pragma unroll
        for (int kt = 0; kt < 4; ++kt)
            s[kt] = __builtin_amdgcn_mfma_f32_16x16x32_bf16(kbuf[cur][kt][lane], qf, zero, 0, 0, 0);
        __builtin_amdgcn_s_setprio(0);

        float ryb = ry_s[t][wq];
        #pragma unroll
        for (int kt = 0; kt < 4; ++kt) {
            #pragma unroll
            for (int r = 0; r < 4; ++r)
                s[kt][r] += rxr[kt * 4 + r] + ryb + mbuf[cur][16 * kt + 4 * g + r];
        }

        float mloc = s[0][0];
        #pragma unroll
        for (int kt = 0; kt < 4; ++kt)
            #pragma unroll
            for (int r = 0; r < 4; ++r) mloc = fmaxf(mloc, s[kt][r]);
        mloc = fmaxf(mloc, __shfl_xor(mloc, 16));
        mloc = fmaxf(mloc, __shfl_xor(mloc, 32));
        float mnew = fmaxf(m_run, mloc);
        float fsc  = __expf(m_run - mnew);
        float psum = 0.f;
        #pragma unroll
        for (int kt = 0; kt < 4; ++kt)
            #pragma unroll
            for (int r = 0; r < 4; ++r) {
                float pv = __expf(s[kt][r] - mnew);
                s[kt][r] = pv;
                psum += pv;
            }
        psum += __shfl_xor(psum, 16);
        psum += __shfl_xor(psum, 32);
        l_run = l_run * fsc + psum;
        m_run = mnew;
        cacc0 *= fsc;
        cacc1 *= fsc;

        #pragma unroll
        for (int kt = 0; kt < 4; ++kt) {
            unsigned d0 = packbf2(s[kt][0], s[kt][1]);
            unsigned d1 = packbf2(s[kt][2], s[kt][3]);
            int lt = 16 * ((2 * kt + (g >> 1)) & 3) + q15;
            uint2v* dst = (uint2v*)&pbuf[w][kt >> 1][lt][2 * (g & 1)];
            *dst = (uint2v){d0, d1};
        }

        __builtin_amdgcn_s_setprio(1);
        #pragma unroll
        for (int sk = 0; sk < 2; ++sk) {
            short8 pf = *(const short8*)&pbuf[w][sk][lane][0];
            cacc0 = __builtin_amdgcn_mfma_f32_16x16x32_bf16(vbuf[cur][sk * 2 + 0][lane], pf, cacc0, 0, 0, 0);
            cacc1 = __builtin_amdgcn_mfma_f32_16x16x32_bf16(vbuf[cur][sk * 2 + 1][lane], pf, cacc1, 0, 0, 0);
        }
        __builtin_amdgcn_s_setprio(0);

        if (t < NT - 1) {
            kbuf[cur ^ 1][sr >> 4][(sr & 15) + 16 * sc] = rk;
            vbuf[cur ^ 1][(vc >> 2) * 2 + (vd >> 4)][16 * (vc & 3) + (vd & 15)] = rv;
            if (tid < 64) mbuf[cur ^ 1][tid] = rm;
        }
        __syncthreads();
        cur ^= 1;
    }

    size_t prow = (size_t)(sp * NB + b) * NQP + gq;
    float* pc = pctx + prow * DIMM + h * HD;
    #pragma unroll
    for (int r = 0; r < 4; ++r) {
        pc[4 * g + r]      = cacc0[r];
        pc[16 + 4 * g + r] = cacc1[r];
    }
    if (g == 0) {
        float2 v; v.x = m_run; v.y = l_run;
        pml[prow * NHEAD + h] = v;
    }
}

// ---------------------------------------------------------------------------
// Combine the 4 KV-split partials (unchanged, verified).
// ---------------------------------------------------------------------------
__global__ __launch_bounds__(256) void attn_reduce(
    const float* __restrict__ pctx, const float2* __restrict__ pml,
    float* __restrict__ CTX)
{
    const int bq = blockIdx.x;
    const int b = bq / NQ, q = bq - b * NQ;
    const int c = threadIdx.x;
    const int h = c >> 5;

    float m[SPLIT], l[SPLIT];
    #pragma unroll
    for (int sp = 0; sp < SPLIT; ++sp) {
        float2 v = pml[((size_t)(sp * NB + b) * NQP + q) * NHEAD + h];
        m[sp] = v.x; l[sp] = v.y;
    }
    float ms = fmaxf(fmaxf(m[0], m[1]), fmaxf(m[2], m[3]));
    float L = 0.f, acc = 0.f;
    #pragma unroll
    for (int sp = 0; sp < SPLIT; ++sp) {
        float wgt = __expf(m[sp] - ms);
        L   += wgt * l[sp];
        acc += wgt * pctx[((size_t)(sp * NB + b) * NQP + q) * DIMM + c];
    }
    CTX[(size_t)bq * DIMM + c] = acc / L;
}

// ---------------------------------------------------------------------------
// fp32 GEMM for the output projection (unchanged, verified).
// ---------------------------------------------------------------------------
__global__ __launch_bounds__(256) void gemm_bias_f32(
    const float* __restrict__ A, const float* __restrict__ W,
    const float* __restrict__ bias, float* __restrict__ C,
    int M, int N, int K)
{
    __shared__ float As[32][33];
    __shared__ float Ws[32][33];
    const int t  = threadIdx.x;
    const int tr = t >> 4;
    const int tc = t & 15;
    const int brow = blockIdx.y * 32;
    const int bcol = blockIdx.x * 32;
    float acc00 = 0.f, acc01 = 0.f, acc10 = 0.f, acc11 = 0.f;

    for (int kt = 0; kt < K; kt += 32) {
        #pragma unroll
        for (int i = 0; i < 4; ++i) {
            int idx = t + i * 256;
            int r = idx >> 5, c = idx & 31;
            int gr = brow + r;
            As[r][c] = (gr < M) ? A[(size_t)gr * K + kt + c] : 0.f;
            Ws[r][c] = W[(size_t)(bcol + r) * K + kt + c];
        }
        __syncthreads();
        #pragma unroll 8
        for (int k = 0; k < 32; ++k) {
            float a0 = As[tr * 2][k], a1 = As[tr * 2 + 1][k];
            float w0 = Ws[tc * 2][k], w1 = Ws[tc * 2 + 1][k];
            acc00 += a0 * w0; acc01 += a0 * w1;
            acc10 += a1 * w0; acc11 += a1 * w1;
        }
        __syncthreads();
    }
    int gc0 = bcol + tc * 2, gc1 = gc0 + 1;
    int gr0 = brow + tr * 2, gr1 = gr0 + 1;
    if (gr0 < M) {
        C[(size_t)gr0 * N + gc0] = acc00 + bias[gc0];
        C[(size_t)gr0 * N + gc1] = acc01 + bias[gc1];
    }
    if (gr1 < M) {
        C[(size_t)gr1 * N + gc0] = acc10 + bias[gc0];
        C[(size_t)gr1 * N + gc1] = acc11 + bias[gc1];
    }
}

// ---------------------------------------------------------------------------
extern "C" void kernel_launch(void* const* d_in, const int* in_sizes, int n_in,
                              void* d_out, int out_size, void* d_ws, size_t ws_size,
                              hipStream_t stream)
{
    const float* hs   = (const float*)d_in[0];
    const float* rp   = (const float*)d_in[1];
    const float* kv   = (const float*)d_in[2];
    const int*   msk  = (const int*)d_in[4];
    const float* m1w1 = (const float*)d_in[5];
    const float* m1b1 = (const float*)d_in[6];
    const float* m1w2 = (const float*)d_in[7];
    const float* m2w1 = (const float*)d_in[8];
    const float* m2b1 = (const float*)d_in[9];
    const float* m2w2 = (const float*)d_in[10];
    const float* q_w  = (const float*)d_in[11];
    const float* q_b  = (const float*)d_in[12];
    const float* k_w  = (const float*)d_in[13];
    const float* k_b  = (const float*)d_in[14];
    const float* v_w  = (const float*)d_in[15];
    const float* v_b  = (const float*)d_in[16];
    const float* o_w  = (const float*)d_in[17];
    const float* o_b  = (const float*)d_in[18];
    float* out = (float*)d_out;

    char* p = (char*)d_ws;
    float* RX   = (float*)p; p += (size_t)NB * NQ * NHEAD * GRID * 4;
    float* RY   = (float*)p; p += (size_t)NB * NQ * NHEAD * GRID * 4;
    float* CTX  = (float*)p; p += (size_t)NB * NQ * DIMM * 4;
    u16*   Qbf  = (u16*)p;   p += (size_t)1920 * DIMM * 2;
    u16*   Kbf  = (u16*)p;   p += (size_t)NB * NKV * DIMM * 2;
    u16*   Vt   = (u16*)p;   p += (size_t)NB * NHEAD * HD * NKV * 2;
    float* WPKG = (float*)p; p += (size_t)2 * RPEH * 16 * 4;

    // union region: {bf16 conv buffers} (conv..proj) / {attn partials} (attn..reduce)
    char* u = p;
    u16* hsbf = (u16*)u;
    u16* kvbf = hsbf + (size_t)1920 * DIMM;
    u16* qwbf = kvbf + (size_t)NB * NKV * DIMM;
    u16* kwbf = qwbf + (size_t)DIMM * DIMM;
    u16* vwbf = kwbf + (size_t)DIMM * DIMM;
    float*  pctx = (float*)u;
    float2* pml  = (float2*)(pctx + (size_t)SPLIT * NB * NQP * DIMM);

    const float scale = 0.17677669529663687f;  // 32^-0.5

    // 0) pack RPE weights for scalar-load path (16-float records)
    rpe_pack<<<64, 256, 0, stream>>>(m1w1, m1b1, m1w2, m2w1, m2b1, m2w2, WPKG);

    // 1) fp32 -> bf16 conversion
    conv_bf16<<<1024, 256, 0, stream>>>(hs, kv, q_w, k_w, v_w,
                                        hsbf, kvbf, qwbf, kwbf, vwbf);

    // 2) Q projection (bf16 MFMA, scale folded)
    proj_mfma<<<dim3(15, 2, 1), 256, 0, stream>>>(
        hsbf, qwbf, q_b, nullptr, nullptr, Qbf, nullptr, NB * NQ, scale);

    // 3) K + V projections fused (z=0 -> K row-major, z=1 -> V transposed)
    proj_mfma<<<dim3(64, 2, 2), 256, 0, stream>>>(
        kvbf, kwbf, k_b, vwbf, v_b, Kbf, Vt, NB * NKV, 1.f);

    // 4) RPE MLPs (900 blocks x 4 waves; block-uniform scalar-load weights)
    rpe_kernel<<<900, 256, 0, stream>>>(rp, WPKG, RX, RY);

    // 5) MFMA attention, KV-split x4
    attn_mfma<<<dim3((NQ + 63) / 64, NHEAD, NB * SPLIT), 256, 0, stream>>>(
        Qbf, Kbf, Vt, RX, RY, msk, pctx, pml);

    // 6) combine partials
    attn_reduce<<<NB * NQ, 256, 0, stream>>>(pctx, pml, CTX);

    // 7) Output projection (fp32)
    gemm_bias_f32<<<dim3(DIMM / 32, (NB * NQ + 31) / 32), 256, 0, stream>>>(
        CTX, o_w, o_b, out, NB * NQ, DIMM, DIMM);
}

// Round 8
// 146.835 us; speedup vs baseline: 1.8694x; 1.8694x over previous
//
#include <hip/hip_runtime.h>
#include <math.h>

#define NB    2
#define NQ    900
#define NQP   960
#define NKV   4096
#define DIMM  256
#define NHEAD 8
#define HD    32
#define RPEH  512
#define GRID  64
#define SPLIT 4
#define KVSEG 1024
#define NT    16

typedef short short8 __attribute__((ext_vector_type(8)));
typedef float f32x4 __attribute__((ext_vector_type(4)));
typedef unsigned uint2v __attribute__((ext_vector_type(2)));
typedef unsigned short u16;
typedef unsigned short u16x4 __attribute__((ext_vector_type(4)));

__device__ inline u16 f2bf(float f) {
    unsigned u = __builtin_bit_cast(unsigned, f);
    u += 0x7fff + ((u >> 16) & 1);
    return (u16)(u >> 16);
}
__device__ inline unsigned packbf2(float a, float b) {
    unsigned ua = __builtin_bit_cast(unsigned, a);
    ua += 0x7fff + ((ua >> 16) & 1);
    unsigned ub = __builtin_bit_cast(unsigned, b);
    ub += 0x7fff + ((ub >> 16) & 1);
    return (ua >> 16) | (ub & 0xffff0000u);
}

// ---------------------------------------------------------------------------
// fp32 -> bf16 conversion prepass (hs, kv, q_w, k_w, v_w), one launch.
// ---------------------------------------------------------------------------
#define HS4  115200   // 1800*256/4
#define KV4  524288   // 8192*256/4
#define W4   16384    // 256*256/4
__global__ __launch_bounds__(256) void conv_bf16(
    const float* __restrict__ hs, const float* __restrict__ kv,
    const float* __restrict__ qw, const float* __restrict__ kw,
    const float* __restrict__ vw,
    u16* __restrict__ hsbf, u16* __restrict__ kvbf,
    u16* __restrict__ qwbf, u16* __restrict__ kwbf, u16* __restrict__ vwbf)
{
    const int total = HS4 + KV4 + 3 * W4;
    for (int g = blockIdx.x * 256 + threadIdx.x; g < total; g += gridDim.x * 256) {
        const float* s; u16* d; int off;
        if (g < HS4)                       { s = hs; d = hsbf; off = g; }
        else if (g < HS4 + KV4)            { s = kv; d = kvbf; off = g - HS4; }
        else if (g < HS4 + KV4 + W4)       { s = qw; d = qwbf; off = g - HS4 - KV4; }
        else if (g < HS4 + KV4 + 2 * W4)   { s = kw; d = kwbf; off = g - HS4 - KV4 - W4; }
        else                               { s = vw; d = vwbf; off = g - HS4 - KV4 - 2 * W4; }
        f32x4 v = *(const f32x4*)(s + (size_t)off * 4);
        *(u16x4*)(d + (size_t)off * 4) =
            (u16x4){f2bf(v[0]), f2bf(v[1]), f2bf(v[2]), f2bf(v[3])};
    }
}

// ---------------------------------------------------------------------------
// bf16 MFMA projection GEMM (unchanged, verified).
// ---------------------------------------------------------------------------
__global__ __launch_bounds__(256) void proj_mfma(
    const u16* __restrict__ A,
    const u16* __restrict__ W0, const float* __restrict__ B0,
    const u16* __restrict__ W1, const float* __restrict__ B1,
    u16* __restrict__ outRow, u16* __restrict__ outVt,
    int M, float scale)
{
    __shared__ u16 Abuf[2][4096];
    __shared__ u16 Bbuf[2][4096];

    const u16* W = W0; const float* bias = B0; bool vt = false;
    if (blockIdx.z == 1) { W = W1; bias = B1; vt = true; }

    const int t    = threadIdx.x;
    const int lane = t & 63;
    const int w    = t >> 6;
    const int wm   = w >> 1, wn = w & 1;
    const int m0   = blockIdx.x * 128;
    const int n0   = blockIdx.y * 128;

    const int r0 = t >> 2, c0 = t & 3;
    const int r1 = r0 + 64;
    const int s0 = r0 * 4 + (c0 ^ (r0 & 3));
    const int s1 = r1 * 4 + (c0 ^ (r1 & 3));
    const u16* Arow0 = A + (size_t)(m0 + r0) * DIMM + c0 * 8;
    const u16* Arow1 = A + (size_t)(m0 + r1) * DIMM + c0 * 8;
    const u16* Wrow0 = W + (size_t)(n0 + r0) * DIMM + c0 * 8;
    const u16* Wrow1 = W + (size_t)(n0 + r1) * DIMM + c0 * 8;

    const int fr = lane & 15, fkc = lane >> 4;
    int aslot[4], bslot[4];
    #pragma unroll
    for (int f = 0; f < 4; ++f) {
        int ar = wm * 64 + f * 16 + fr;
        int br = wn * 64 + f * 16 + fr;
        aslot[f] = ar * 4 + (fkc ^ (ar & 3));
        bslot[f] = br * 4 + (fkc ^ (br & 3));
    }
    float bv[4];
    #pragma unroll
    for (int f = 0; f < 4; ++f) bv[f] = bias[n0 + wn * 64 + f * 16 + fr];

    f32x4 acc[4][4] = {};

    {
        short8 a0 = *(const short8*)(Arow0);
        short8 a1 = *(const short8*)(Arow1);
        short8 b0 = *(const short8*)(Wrow0);
        short8 b1 = *(const short8*)(Wrow1);
        *(short8*)&Abuf[0][s0 * 8] = a0;
        *(short8*)&Abuf[0][s1 * 8] = a1;
        *(short8*)&Bbuf[0][s0 * 8] = b0;
        *(short8*)&Bbuf[0][s1 * 8] = b1;
    }
    __syncthreads();

    int cur = 0;
    for (int kt = 0; kt < 8; ++kt) {
        short8 na0, na1, nb0, nb1;
        if (kt < 7) {
            int ko = (kt + 1) * 32;
            na0 = *(const short8*)(Arow0 + ko);
            na1 = *(const short8*)(Arow1 + ko);
            nb0 = *(const short8*)(Wrow0 + ko);
            nb1 = *(const short8*)(Wrow1 + ko);
        }
        short8 af[4], bf[4];
        #pragma unroll
        for (int f = 0; f < 4; ++f) {
            af[f] = *(const short8*)&Abuf[cur][aslot[f] * 8];
            bf[f] = *(const short8*)&Bbuf[cur][bslot[f] * 8];
        }
        #pragma unroll
        for (int i = 0; i < 4; ++i)
            #pragma unroll
            for (int j = 0; j < 4; ++j)
                acc[i][j] = __builtin_amdgcn_mfma_f32_16x16x32_bf16(af[i], bf[j], acc[i][j], 0, 0, 0);
        if (kt < 7) {
            *(short8*)&Abuf[cur ^ 1][s0 * 8] = na0;
            *(short8*)&Abuf[cur ^ 1][s1 * 8] = na1;
            *(short8*)&Bbuf[cur ^ 1][s0 * 8] = nb0;
            *(short8*)&Bbuf[cur ^ 1][s1 * 8] = nb1;
        }
        __syncthreads();
        cur ^= 1;
    }

    #pragma unroll
    for (int i = 0; i < 4; ++i) {
        int mbase = m0 + wm * 64 + i * 16 + 4 * fkc;
        #pragma unroll
        for (int j = 0; j < 4; ++j) {
            int n = n0 + wn * 64 + j * 16 + fr;
            #pragma unroll
            for (int r = 0; r < 4; ++r) {
                int gm = mbase + r;
                if (gm < M) {
                    float v = (acc[i][j][r] + bv[j]) * scale;
                    if (!vt) {
                        outRow[(size_t)gm * DIMM + n] = f2bf(v);
                    } else {
                        int bb = gm >> 12, kvi = gm & 4095;
                        int hh = n >> 5, dd = n & 31;
                        outVt[(size_t)((bb * NHEAD + hh) * HD + dd) * NKV + kvi] = f2bf(v);
                    }
                }
            }
        }
    }
}

// ---------------------------------------------------------------------------
// RPE MLPs, LDS-broadcast weights, G=2 tasks per wave.
// Block = 128 threads = 2 waves; block handles 4 bq, one m (m-pure).
// Per r-iteration: 3 ds_read_b128 broadcasts serve TWO bq tasks ->
// LDS-return cost per task halved vs R5's G=1 (the measured bottleneck).
// ---------------------------------------------------------------------------
__global__ __launch_bounds__(128) void rpe_kernel(
    const float* __restrict__ ref_pts,
    const float* __restrict__ w1x, const float* __restrict__ b1x,
    const float* __restrict__ w2x,
    const float* __restrict__ w1y, const float* __restrict__ b1y,
    const float* __restrict__ w2y,
    float* __restrict__ rpex, float* __restrict__ rpey)
{
    __shared__ f32x4 wpk[RPEH];            // {a, b, bias, a+b}   8 KB
    __shared__ float w2t[RPEH][NHEAD];     // transposed layer-2  16 KB

    const int t   = threadIdx.x;
    const int m   = blockIdx.x & 1;
    const int bq0 = (blockIdx.x >> 1) * 4;

    const float* w1 = m ? w1y : w1x;
    const float* b1 = m ? b1y : b1x;
    const float* w2 = m ? w2y : w2x;
    for (int r = t; r < RPEH; r += 128) {
        float a = w1[r * 2], b = w1[r * 2 + 1];
        wpk[r] = (f32x4){a, b, b1[r], a + b};
    }
    for (int i = t; i < RPEH * NHEAD; i += 128) {
        int h = i >> 9, r = i & 511;
        w2t[r][h] = w2[h * RPEH + r];
    }
    __syncthreads();

    const int lane = t & 63;
    const int wv   = t >> 6;
    const int bqA  = bq0 + wv * 2;
    const int bqB  = bqA + 1;
    const float p  = (lane + 0.5f) * 16.f;

    const float* qA = ref_pts + (size_t)bqA * 4;
    const float* qB = ref_pts + (size_t)bqB * 4;
    const float cA = m ? qA[1] : qA[0];
    const float sA = m ? qA[3] : qA[2];
    const float cB = m ? qB[1] : qB[0];
    const float sB = m ? qB[3] : qB[2];
    const float loA = (cA - sA * 0.5f) * 1024.f;
    const float hiA = (cA + sA * 0.5f) * 1024.f;
    const float loB = (cB - sB * 0.5f) * 1024.f;
    const float hiB = (cB + sB * 0.5f) * 1024.f;

    float2 accA[4] = {};
    float2 accB[4] = {};
    #pragma unroll 4
    for (int r = 0; r < RPEH; ++r) {
        f32x4 W  = wpk[r];
        f32x4 u0 = *(const f32x4*)&w2t[r][0];
        f32x4 u1 = *(const f32x4*)&w2t[r][4];
        float bp = W[3] * p;
        float alA  = W[0] * loA + W[1] * hiA + W[2];
        float alB  = W[0] * loB + W[1] * hiB + W[2];
        float hidA = fmaxf(alA - bp, 0.f);
        float hidB = fmaxf(alB - bp, 0.f);
        accA[0].x += u0[0] * hidA;  accA[0].y += u0[1] * hidA;
        accA[1].x += u0[2] * hidA;  accA[1].y += u0[3] * hidA;
        accA[2].x += u1[0] * hidA;  accA[2].y += u1[1] * hidA;
        accA[3].x += u1[2] * hidA;  accA[3].y += u1[3] * hidA;
        accB[0].x += u0[0] * hidB;  accB[0].y += u0[1] * hidB;
        accB[1].x += u0[2] * hidB;  accB[1].y += u0[3] * hidB;
        accB[2].x += u1[0] * hidB;  accB[2].y += u1[1] * hidB;
        accB[3].x += u1[2] * hidB;  accB[3].y += u1[3] * hidB;
    }

    float* outp = m ? rpey : rpex;
    size_t baseA = (size_t)bqA * (NHEAD * GRID) + lane;
    size_t baseB = (size_t)bqB * (NHEAD * GRID) + lane;
    #pragma unroll
    for (int j = 0; j < 4; ++j) {
        outp[baseA + (2 * j) * GRID]     = accA[j].x;
        outp[baseA + (2 * j + 1) * GRID] = accA[j].y;
        outp[baseB + (2 * j) * GRID]     = accB[j].x;
        outp[baseB + (2 * j + 1) * GRID] = accB[j].y;
    }
}

// ---------------------------------------------------------------------------
// MFMA attention, KV-split flash-decode (unchanged, verified).
// ---------------------------------------------------------------------------
__global__ __launch_bounds__(256) void attn_mfma(
    const u16* __restrict__ Qbf, const u16* __restrict__ Kbf,
    const u16* __restrict__ Vt,
    const float* __restrict__ RX, const float* __restrict__ RY,
    const int* __restrict__ mask,
    float* __restrict__ pctx, float2* __restrict__ pml)
{
    __shared__ short8 kbuf[2][4][64];
    __shared__ short8 vbuf[2][4][64];
    __shared__ unsigned pbuf[4][2][64][4];
    __shared__ float ry_s[16][68];
    __shared__ float mbuf[2][64];

    const int tid  = threadIdx.x;
    const int lane = tid & 63;
    const int w    = tid >> 6;
    const int q15  = lane & 15;
    const int g    = lane >> 4;
    const int qt = blockIdx.x, h = blockIdx.y;
    const int b  = blockIdx.z >> 2;
    const int sp = blockIdx.z & 3;
    const int q0 = qt * 64;
    const int wq = w * 16 + q15;
    const int gq = q0 + wq;
    const bool qok = gq < NQ;
    const int kv0g = sp * KVSEG;

    float rxr[16];
    {
        const float* rxrow = RX + (size_t)(b * NQ + (qok ? gq : 0)) * (NHEAD * GRID) + h * GRID;
        #pragma unroll
        for (int kt = 0; kt < 4; ++kt)
            #pragma unroll
            for (int r = 0; r < 4; ++r)
                rxr[kt * 4 + r] = qok ? rxrow[16 * kt + 4 * g + r] : 0.f;
    }
    for (int idx = tid; idx < 16 * 64; idx += 256) {
        int y = idx & 15, q = idx >> 4;
        int gq2 = q0 + q;
        ry_s[y][q] = (gq2 < NQ)
            ? RY[(size_t)(b * NQ + gq2) * (NHEAD * GRID) + h * GRID + sp * 16 + y] : 0.f;
    }

    short8 qf = *(const short8*)(Qbf + ((size_t)(b * NQ + gq)) * DIMM + h * HD + 8 * g);

    const int sr = tid >> 2, sc = tid & 3;
    const int vd = tid >> 3, vc = tid & 7;
    const size_t kbase = ((size_t)(b * NKV + kv0g + sr)) * DIMM + h * HD + 8 * sc;
    const size_t vbase = ((size_t)((b * NHEAD + h) * HD + vd)) * NKV + kv0g + 8 * vc;

    kbuf[0][sr >> 4][(sr & 15) + 16 * sc] = *(const short8*)(Kbf + kbase);
    vbuf[0][(vc >> 2) * 2 + (vd >> 4)][16 * (vc & 3) + (vd & 15)] = *(const short8*)(Vt + vbase);
    if (tid < 64) mbuf[0][tid] = -100.f * (float)mask[b * NKV + kv0g + tid];
    __syncthreads();

    f32x4 cacc0 = {0.f, 0.f, 0.f, 0.f};
    f32x4 cacc1 = {0.f, 0.f, 0.f, 0.f};
    float m_run = -1e30f, l_run = 0.f;
    int cur = 0;

    for (int t = 0; t < NT; ++t) {
        short8 rk = {}, rv = {};
        float rm = 0.f;
        if (t < NT - 1) {
            size_t kvn = (size_t)(t + 1) * 64;
            rk = *(const short8*)(Kbf + kbase + kvn * DIMM);
            rv = *(const short8*)(Vt + vbase + kvn);
            if (tid < 64) rm = -100.f * (float)mask[b * NKV + kv0g + kvn + tid];
        }

        f32x4 zero = {0.f, 0.f, 0.f, 0.f};
        f32x4 s[4];
        __builtin_amdgcn_s_setprio(1);
        #pragma unroll
        for (int kt = 0; kt < 4; ++kt)
            s[kt] = __builtin_amdgcn_mfma_f32_16x16x32_bf16(kbuf[cur][kt][lane], qf, zero, 0, 0, 0);
        __builtin_amdgcn_s_setprio(0);

        float ryb = ry_s[t][wq];
        #pragma unroll
        for (int kt = 0; kt < 4; ++kt) {
            #pragma unroll
            for (int r = 0; r < 4; ++r)
                s[kt][r] += rxr[kt * 4 + r] + ryb + mbuf[cur][16 * kt + 4 * g + r];
        }

        float mloc = s[0][0];
        #pragma unroll
        for (int kt = 0; kt < 4; ++kt)
            #pragma unroll
            for (int r = 0; r < 4; ++r) mloc = fmaxf(mloc, s[kt][r]);
        mloc = fmaxf(mloc, __shfl_xor(mloc, 16));
        mloc = fmaxf(mloc, __shfl_xor(mloc, 32));
        float mnew = fmaxf(m_run, mloc);
        float fsc  = __expf(m_run - mnew);
        float psum = 0.f;
        #pragma unroll
        for (int kt = 0; kt < 4; ++kt)
            #pragma unroll
            for (int r = 0; r < 4; ++r) {
                float pv = __expf(s[kt][r] - mnew);
                s[kt][r] = pv;
                psum += pv;
            }
        psum += __shfl_xor(psum, 16);
        psum += __shfl_xor(psum, 32);
        l_run = l_run * fsc + psum;
        m_run = mnew;
        cacc0 *= fsc;
        cacc1 *= fsc;

        #pragma unroll
        for (int kt = 0; kt < 4; ++kt) {
            unsigned d0 = packbf2(s[kt][0], s[kt][1]);
            unsigned d1 = packbf2(s[kt][2], s[kt][3]);
            int lt = 16 * ((2 * kt + (g >> 1)) & 3) + q15;
            uint2v* dst = (uint2v*)&pbuf[w][kt >> 1][lt][2 * (g & 1)];
            *dst = (uint2v){d0, d1};
        }

        __builtin_amdgcn_s_setprio(1);
        #pragma unroll
        for (int sk = 0; sk < 2; ++sk) {
            short8 pf = *(const short8*)&pbuf[w][sk][lane][0];
            cacc0 = __builtin_amdgcn_mfma_f32_16x16x32_bf16(vbuf[cur][sk * 2 + 0][lane], pf, cacc0, 0, 0, 0);
            cacc1 = __builtin_amdgcn_mfma_f32_16x16x32_bf16(vbuf[cur][sk * 2 + 1][lane], pf, cacc1, 0, 0, 0);
        }
        __builtin_amdgcn_s_setprio(0);

        if (t < NT - 1) {
            kbuf[cur ^ 1][sr >> 4][(sr & 15) + 16 * sc] = rk;
            vbuf[cur ^ 1][(vc >> 2) * 2 + (vd >> 4)][16 * (vc & 3) + (vd & 15)] = rv;
            if (tid < 64) mbuf[cur ^ 1][tid] = rm;
        }
        __syncthreads();
        cur ^= 1;
    }

    size_t prow = (size_t)(sp * NB + b) * NQP + gq;
    float* pc = pctx + prow * DIMM + h * HD;
    #pragma unroll
    for (int r = 0; r < 4; ++r) {
        pc[4 * g + r]      = cacc0[r];
        pc[16 + 4 * g + r] = cacc1[r];
    }
    if (g == 0) {
        float2 v; v.x = m_run; v.y = l_run;
        pml[prow * NHEAD + h] = v;
    }
}

// ---------------------------------------------------------------------------
// Combine the 4 KV-split partials (unchanged, verified).
// ---------------------------------------------------------------------------
__global__ __launch_bounds__(256) void attn_reduce(
    const float* __restrict__ pctx, const float2* __restrict__ pml,
    float* __restrict__ CTX)
{
    const int bq = blockIdx.x;
    const int b = bq / NQ, q = bq - b * NQ;
    const int c = threadIdx.x;
    const int h = c >> 5;

    float m[SPLIT], l[SPLIT];
    #pragma unroll
    for (int sp = 0; sp < SPLIT; ++sp) {
        float2 v = pml[((size_t)(sp * NB + b) * NQP + q) * NHEAD + h];
        m[sp] = v.x; l[sp] = v.y;
    }
    float ms = fmaxf(fmaxf(m[0], m[1]), fmaxf(m[2], m[3]));
    float L = 0.f, acc = 0.f;
    #pragma unroll
    for (int sp = 0; sp < SPLIT; ++sp) {
        float wgt = __expf(m[sp] - ms);
        L   += wgt * l[sp];
        acc += wgt * pctx[((size_t)(sp * NB + b) * NQP + q) * DIMM + c];
    }
    CTX[(size_t)bq * DIMM + c] = acc / L;
}

// ---------------------------------------------------------------------------
// fp32 GEMM for the output projection (unchanged, verified).
// ---------------------------------------------------------------------------
__global__ __launch_bounds__(256) void gemm_bias_f32(
    const float* __restrict__ A, const float* __restrict__ W,
    const float* __restrict__ bias, float* __restrict__ C,
    int M, int N, int K)
{
    __shared__ float As[32][33];
    __shared__ float Ws[32][33];
    const int t  = threadIdx.x;
    const int tr = t >> 4;
    const int tc = t & 15;
    const int brow = blockIdx.y * 32;
    const int bcol = blockIdx.x * 32;
    float acc00 = 0.f, acc01 = 0.f, acc10 = 0.f, acc11 = 0.f;

    for (int kt = 0; kt < K; kt += 32) {
        #pragma unroll
        for (int i = 0; i < 4; ++i) {
            int idx = t + i * 256;
            int r = idx >> 5, c = idx & 31;
            int gr = brow + r;
            As[r][c] = (gr < M) ? A[(size_t)gr * K + kt + c] : 0.f;
            Ws[r][c] = W[(size_t)(bcol + r) * K + kt + c];
        }
        __syncthreads();
        #pragma unroll 8
        for (int k = 0; k < 32; ++k) {
            float a0 = As[tr * 2][k], a1 = As[tr * 2 + 1][k];
            float w0 = Ws[tc * 2][k], w1 = Ws[tc * 2 + 1][k];
            acc00 += a0 * w0; acc01 += a0 * w1;
            acc10 += a1 * w0; acc11 += a1 * w1;
        }
        __syncthreads();
    }
    int gc0 = bcol + tc * 2, gc1 = gc0 + 1;
    int gr0 = brow + tr * 2, gr1 = gr0 + 1;
    if (gr0 < M) {
        C[(size_t)gr0 * N + gc0] = acc00 + bias[gc0];
        C[(size_t)gr0 * N + gc1] = acc01 + bias[gc1];
    }
    if (gr1 < M) {
        C[(size_t)gr1 * N + gc0] = acc10 + bias[gc0];
        C[(size_t)gr1 * N + gc1] = acc11 + bias[gc1];
    }
}

// ---------------------------------------------------------------------------
extern "C" void kernel_launch(void* const* d_in, const int* in_sizes, int n_in,
                              void* d_out, int out_size, void* d_ws, size_t ws_size,
                              hipStream_t stream)
{
    const float* hs   = (const float*)d_in[0];
    const float* rp   = (const float*)d_in[1];
    const float* kv   = (const float*)d_in[2];
    const int*   msk  = (const int*)d_in[4];
    const float* m1w1 = (const float*)d_in[5];
    const float* m1b1 = (const float*)d_in[6];
    const float* m1w2 = (const float*)d_in[7];
    const float* m2w1 = (const float*)d_in[8];
    const float* m2b1 = (const float*)d_in[9];
    const float* m2w2 = (const float*)d_in[10];
    const float* q_w  = (const float*)d_in[11];
    const float* q_b  = (const float*)d_in[12];
    const float* k_w  = (const float*)d_in[13];
    const float* k_b  = (const float*)d_in[14];
    const float* v_w  = (const float*)d_in[15];
    const float* v_b  = (const float*)d_in[16];
    const float* o_w  = (const float*)d_in[17];
    const float* o_b  = (const float*)d_in[18];
    float* out = (float*)d_out;

    char* p = (char*)d_ws;
    float* RX   = (float*)p; p += (size_t)NB * NQ * NHEAD * GRID * 4;
    float* RY   = (float*)p; p += (size_t)NB * NQ * NHEAD * GRID * 4;
    float* CTX  = (float*)p; p += (size_t)NB * NQ * DIMM * 4;
    u16*   Qbf  = (u16*)p;   p += (size_t)1920 * DIMM * 2;
    u16*   Kbf  = (u16*)p;   p += (size_t)NB * NKV * DIMM * 2;
    u16*   Vt   = (u16*)p;   p += (size_t)NB * NHEAD * HD * NKV * 2;

    // union region: {bf16 conv buffers} (conv..proj) / {attn partials} (attn..reduce)
    char* u = p;
    u16* hsbf = (u16*)u;
    u16* kvbf = hsbf + (size_t)1920 * DIMM;
    u16* qwbf = kvbf + (size_t)NB * NKV * DIMM;
    u16* kwbf = qwbf + (size_t)DIMM * DIMM;
    u16* vwbf = kwbf + (size_t)DIMM * DIMM;
    float*  pctx = (float*)u;
    float2* pml  = (float2*)(pctx + (size_t)SPLIT * NB * NQP * DIMM);

    const float scale = 0.17677669529663687f;  // 32^-0.5

    // 1) fp32 -> bf16 conversion
    conv_bf16<<<1024, 256, 0, stream>>>(hs, kv, q_w, k_w, v_w,
                                        hsbf, kvbf, qwbf, kwbf, vwbf);

    // 2) Q projection (bf16 MFMA, scale folded)
    proj_mfma<<<dim3(15, 2, 1), 256, 0, stream>>>(
        hsbf, qwbf, q_b, nullptr, nullptr, Qbf, nullptr, NB * NQ, scale);

    // 3) K + V projections fused (z=0 -> K row-major, z=1 -> V transposed)
    proj_mfma<<<dim3(64, 2, 2), 256, 0, stream>>>(
        kvbf, kwbf, k_b, vwbf, v_b, Kbf, Vt, NB * NKV, 1.f);

    // 4) RPE MLPs (900 blocks x 128 threads; LDS broadcast, 2 tasks/wave)
    rpe_kernel<<<900, 128, 0, stream>>>(rp, m1w1, m1b1, m1w2,
                                        m2w1, m2b1, m2w2, RX, RY);

    // 5) MFMA attention, KV-split x4
    attn_mfma<<<dim3((NQ + 63) / 64, NHEAD, NB * SPLIT), 256, 0, stream>>>(
        Qbf, Kbf, Vt, RX, RY, msk, pctx, pml);

    // 6) combine partials
    attn_reduce<<<NB * NQ, 256, 0, stream>>>(pctx, pml, CTX);

    // 7) Output projection (fp32)
    gemm_bias_f32<<<dim3(DIMM / 32, (NB * NQ + 31) / 32), 256, 0, stream>>>(
        CTX, o_w, o_b, out, NB * NQ, DIMM, DIMM);
}

// Round 9
// 144.272 us; speedup vs baseline: 1.9026x; 1.0178x over previous
//
#include <hip/hip_runtime.h>
#include <math.h>

#define NB    2
#define NQ    900
#define NQP   960
#define NKV   4096
#define DIMM  256
#define NHEAD 8
#define HD    32
#define RPEH  512
#define GRID  64
#define SPLIT 4
#define KVSEG 1024
#define NT    16

typedef short short8 __attribute__((ext_vector_type(8)));
typedef float f32x4 __attribute__((ext_vector_type(4)));
typedef unsigned uint2v __attribute__((ext_vector_type(2)));
typedef unsigned short u16;
typedef unsigned short u16x4 __attribute__((ext_vector_type(4)));

__device__ inline u16 f2bf(float f) {
    unsigned u = __builtin_bit_cast(unsigned, f);
    u += 0x7fff + ((u >> 16) & 1);
    return (u16)(u >> 16);
}
__device__ inline unsigned packbf2(float a, float b) {
    unsigned ua = __builtin_bit_cast(unsigned, a);
    ua += 0x7fff + ((ua >> 16) & 1);
    unsigned ub = __builtin_bit_cast(unsigned, b);
    ub += 0x7fff + ((ub >> 16) & 1);
    return (ua >> 16) | (ub & 0xffff0000u);
}

// ---------------------------------------------------------------------------
// fp32 -> bf16 conversion prepass (hs, kv, q_w, k_w, v_w), one launch.
// ---------------------------------------------------------------------------
#define HS4  115200   // 1800*256/4
#define KV4  524288   // 8192*256/4
#define W4   16384    // 256*256/4
__global__ __launch_bounds__(256) void conv_bf16(
    const float* __restrict__ hs, const float* __restrict__ kv,
    const float* __restrict__ qw, const float* __restrict__ kw,
    const float* __restrict__ vw,
    u16* __restrict__ hsbf, u16* __restrict__ kvbf,
    u16* __restrict__ qwbf, u16* __restrict__ kwbf, u16* __restrict__ vwbf)
{
    const int total = HS4 + KV4 + 3 * W4;
    for (int g = blockIdx.x * 256 + threadIdx.x; g < total; g += gridDim.x * 256) {
        const float* s; u16* d; int off;
        if (g < HS4)                       { s = hs; d = hsbf; off = g; }
        else if (g < HS4 + KV4)            { s = kv; d = kvbf; off = g - HS4; }
        else if (g < HS4 + KV4 + W4)       { s = qw; d = qwbf; off = g - HS4 - KV4; }
        else if (g < HS4 + KV4 + 2 * W4)   { s = kw; d = kwbf; off = g - HS4 - KV4 - W4; }
        else                               { s = vw; d = vwbf; off = g - HS4 - KV4 - 2 * W4; }
        f32x4 v = *(const f32x4*)(s + (size_t)off * 4);
        *(u16x4*)(d + (size_t)off * 4) =
            (u16x4){f2bf(v[0]), f2bf(v[1]), f2bf(v[2]), f2bf(v[3])};
    }
}

// ---------------------------------------------------------------------------
// bf16 MFMA projection GEMM (unchanged, verified).
// ---------------------------------------------------------------------------
__global__ __launch_bounds__(256) void proj_mfma(
    const u16* __restrict__ A,
    const u16* __restrict__ W0, const float* __restrict__ B0,
    const u16* __restrict__ W1, const float* __restrict__ B1,
    u16* __restrict__ outRow, u16* __restrict__ outVt,
    int M, float scale)
{
    __shared__ u16 Abuf[2][4096];
    __shared__ u16 Bbuf[2][4096];

    const u16* W = W0; const float* bias = B0; bool vt = false;
    if (blockIdx.z == 1) { W = W1; bias = B1; vt = true; }

    const int t    = threadIdx.x;
    const int lane = t & 63;
    const int w    = t >> 6;
    const int wm   = w >> 1, wn = w & 1;
    const int m0   = blockIdx.x * 128;
    const int n0   = blockIdx.y * 128;

    const int r0 = t >> 2, c0 = t & 3;
    const int r1 = r0 + 64;
    const int s0 = r0 * 4 + (c0 ^ (r0 & 3));
    const int s1 = r1 * 4 + (c0 ^ (r1 & 3));
    const u16* Arow0 = A + (size_t)(m0 + r0) * DIMM + c0 * 8;
    const u16* Arow1 = A + (size_t)(m0 + r1) * DIMM + c0 * 8;
    const u16* Wrow0 = W + (size_t)(n0 + r0) * DIMM + c0 * 8;
    const u16* Wrow1 = W + (size_t)(n0 + r1) * DIMM + c0 * 8;

    const int fr = lane & 15, fkc = lane >> 4;
    int aslot[4], bslot[4];
    #pragma unroll
    for (int f = 0; f < 4; ++f) {
        int ar = wm * 64 + f * 16 + fr;
        int br = wn * 64 + f * 16 + fr;
        aslot[f] = ar * 4 + (fkc ^ (ar & 3));
        bslot[f] = br * 4 + (fkc ^ (br & 3));
    }
    float bv[4];
    #pragma unroll
    for (int f = 0; f < 4; ++f) bv[f] = bias[n0 + wn * 64 + f * 16 + fr];

    f32x4 acc[4][4] = {};

    {
        short8 a0 = *(const short8*)(Arow0);
        short8 a1 = *(const short8*)(Arow1);
        short8 b0 = *(const short8*)(Wrow0);
        short8 b1 = *(const short8*)(Wrow1);
        *(short8*)&Abuf[0][s0 * 8] = a0;
        *(short8*)&Abuf[0][s1 * 8] = a1;
        *(short8*)&Bbuf[0][s0 * 8] = b0;
        *(short8*)&Bbuf[0][s1 * 8] = b1;
    }
    __syncthreads();

    int cur = 0;
    for (int kt = 0; kt < 8; ++kt) {
        short8 na0, na1, nb0, nb1;
        if (kt < 7) {
            int ko = (kt + 1) * 32;
            na0 = *(const short8*)(Arow0 + ko);
            na1 = *(const short8*)(Arow1 + ko);
            nb0 = *(const short8*)(Wrow0 + ko);
            nb1 = *(const short8*)(Wrow1 + ko);
        }
        short8 af[4], bf[4];
        #pragma unroll
        for (int f = 0; f < 4; ++f) {
            af[f] = *(const short8*)&Abuf[cur][aslot[f] * 8];
            bf[f] = *(const short8*)&Bbuf[cur][bslot[f] * 8];
        }
        #pragma unroll
        for (int i = 0; i < 4; ++i)
            #pragma unroll
            for (int j = 0; j < 4; ++j)
                acc[i][j] = __builtin_amdgcn_mfma_f32_16x16x32_bf16(af[i], bf[j], acc[i][j], 0, 0, 0);
        if (kt < 7) {
            *(short8*)&Abuf[cur ^ 1][s0 * 8] = na0;
            *(short8*)&Abuf[cur ^ 1][s1 * 8] = na1;
            *(short8*)&Bbuf[cur ^ 1][s0 * 8] = nb0;
            *(short8*)&Bbuf[cur ^ 1][s1 * 8] = nb1;
        }
        __syncthreads();
        cur ^= 1;
    }

    #pragma unroll
    for (int i = 0; i < 4; ++i) {
        int mbase = m0 + wm * 64 + i * 16 + 4 * fkc;
        #pragma unroll
        for (int j = 0; j < 4; ++j) {
            int n = n0 + wn * 64 + j * 16 + fr;
            #pragma unroll
            for (int r = 0; r < 4; ++r) {
                int gm = mbase + r;
                if (gm < M) {
                    float v = (acc[i][j][r] + bv[j]) * scale;
                    if (!vt) {
                        outRow[(size_t)gm * DIMM + n] = f2bf(v);
                    } else {
                        int bb = gm >> 12, kvi = gm & 4095;
                        int hh = n >> 5, dd = n & 31;
                        outVt[(size_t)((bb * NHEAD + hh) * HD + dd) * NKV + kvi] = f2bf(v);
                    }
                }
            }
        }
    }
}

// ---------------------------------------------------------------------------
// RPE MLPs: LDS-broadcast weights, G=2 tasks/wave, r-SPLIT across waves.
// Block = 256 threads = 4 waves = 4 bq (m-pure): wave = (bq-pair, r-half).
// Each wave: 256 hidden units x 2 bq -> 3 ds_read_b128 serve 2 tasks,
// 3600 waves total (2x R8) for latency hiding. Halves combined via LDS.
// ---------------------------------------------------------------------------
__global__ __launch_bounds__(256) void rpe_kernel(
    const float* __restrict__ ref_pts,
    const float* __restrict__ w1x, const float* __restrict__ b1x,
    const float* __restrict__ w2x,
    const float* __restrict__ w1y, const float* __restrict__ b1y,
    const float* __restrict__ w2y,
    float* __restrict__ rpex, float* __restrict__ rpey)
{
    __shared__ f32x4 wpk[RPEH];            // {a, b, bias, a+b}   8 KB
    __shared__ float w2t[RPEH][NHEAD];     // transposed layer-2  16 KB
    __shared__ float2 red[2][2][4][64];    // [pair][task][j][lane] 8 KB

    const int t   = threadIdx.x;
    const int m   = blockIdx.x & 1;
    const int bq0 = (blockIdx.x >> 1) * 4;

    const float* w1 = m ? w1y : w1x;
    const float* b1 = m ? b1y : b1x;
    const float* w2 = m ? w2y : w2x;
    for (int r = t; r < RPEH; r += 256) {
        float a = w1[r * 2], b = w1[r * 2 + 1];
        wpk[r] = (f32x4){a, b, b1[r], a + b};
    }
    for (int i = t; i < RPEH * NHEAD; i += 256) {
        int h = i >> 9, r = i & 511;
        w2t[r][h] = w2[h * RPEH + r];
    }
    __syncthreads();

    const int lane = t & 63;
    const int wv   = t >> 6;          // 0..3
    const int pair = wv & 1;          // bq pair within block
    const int rh   = wv >> 1;         // r-half
    const int bqA  = bq0 + pair * 2;
    const int bqB  = bqA + 1;
    const float p  = (lane + 0.5f) * 16.f;

    const float* qA = ref_pts + (size_t)bqA * 4;
    const float* qB = ref_pts + (size_t)bqB * 4;
    const float cA = m ? qA[1] : qA[0];
    const float sA = m ? qA[3] : qA[2];
    const float cB = m ? qB[1] : qB[0];
    const float sB = m ? qB[3] : qB[2];
    const float loA = (cA - sA * 0.5f) * 1024.f;
    const float hiA = (cA + sA * 0.5f) * 1024.f;
    const float loB = (cB - sB * 0.5f) * 1024.f;
    const float hiB = (cB + sB * 0.5f) * 1024.f;

    float2 accA[4] = {};
    float2 accB[4] = {};
    const int r0 = rh * 256;
    #pragma unroll 4
    for (int rr = 0; rr < 256; ++rr) {
        int r = r0 + rr;
        f32x4 W  = wpk[r];
        f32x4 u0 = *(const f32x4*)&w2t[r][0];
        f32x4 u1 = *(const f32x4*)&w2t[r][4];
        float bp = W[3] * p;
        float alA  = W[0] * loA + W[1] * hiA + W[2];
        float alB  = W[0] * loB + W[1] * hiB + W[2];
        float hidA = fmaxf(alA - bp, 0.f);
        float hidB = fmaxf(alB - bp, 0.f);
        accA[0].x += u0[0] * hidA;  accA[0].y += u0[1] * hidA;
        accA[1].x += u0[2] * hidA;  accA[1].y += u0[3] * hidA;
        accA[2].x += u1[0] * hidA;  accA[2].y += u1[1] * hidA;
        accA[3].x += u1[2] * hidA;  accA[3].y += u1[3] * hidA;
        accB[0].x += u0[0] * hidB;  accB[0].y += u0[1] * hidB;
        accB[1].x += u0[2] * hidB;  accB[1].y += u0[3] * hidB;
        accB[2].x += u1[0] * hidB;  accB[2].y += u1[1] * hidB;
        accB[3].x += u1[2] * hidB;  accB[3].y += u1[3] * hidB;
    }

    if (rh == 1) {
        #pragma unroll
        for (int j = 0; j < 4; ++j) {
            red[pair][0][j][lane] = accA[j];
            red[pair][1][j][lane] = accB[j];
        }
    }
    __syncthreads();
    if (rh == 0) {
        float* outp = m ? rpey : rpex;
        size_t baseA = (size_t)bqA * (NHEAD * GRID) + lane;
        size_t baseB = (size_t)bqB * (NHEAD * GRID) + lane;
        #pragma unroll
        for (int j = 0; j < 4; ++j) {
            float2 oA = red[pair][0][j][lane];
            float2 oB = red[pair][1][j][lane];
            outp[baseA + (2 * j) * GRID]     = accA[j].x + oA.x;
            outp[baseA + (2 * j + 1) * GRID] = accA[j].y + oA.y;
            outp[baseB + (2 * j) * GRID]     = accB[j].x + oB.x;
            outp[baseB + (2 * j + 1) * GRID] = accB[j].y + oB.y;
        }
    }
}

// ---------------------------------------------------------------------------
// MFMA attention, KV-split flash-decode (unchanged, verified).
// ---------------------------------------------------------------------------
__global__ __launch_bounds__(256) void attn_mfma(
    const u16* __restrict__ Qbf, const u16* __restrict__ Kbf,
    const u16* __restrict__ Vt,
    const float* __restrict__ RX, const float* __restrict__ RY,
    const int* __restrict__ mask,
    float* __restrict__ pctx, float2* __restrict__ pml)
{
    __shared__ short8 kbuf[2][4][64];
    __shared__ short8 vbuf[2][4][64];
    __shared__ unsigned pbuf[4][2][64][4];
    __shared__ float ry_s[16][68];
    __shared__ float mbuf[2][64];

    const int tid  = threadIdx.x;
    const int lane = tid & 63;
    const int w    = tid >> 6;
    const int q15  = lane & 15;
    const int g    = lane >> 4;
    const int qt = blockIdx.x, h = blockIdx.y;
    const int b  = blockIdx.z >> 2;
    const int sp = blockIdx.z & 3;
    const int q0 = qt * 64;
    const int wq = w * 16 + q15;
    const int gq = q0 + wq;
    const bool qok = gq < NQ;
    const int kv0g = sp * KVSEG;

    float rxr[16];
    {
        const float* rxrow = RX + (size_t)(b * NQ + (qok ? gq : 0)) * (NHEAD * GRID) + h * GRID;
        #pragma unroll
        for (int kt = 0; kt < 4; ++kt)
            #pragma unroll
            for (int r = 0; r < 4; ++r)
                rxr[kt * 4 + r] = qok ? rxrow[16 * kt + 4 * g + r] : 0.f;
    }
    for (int idx = tid; idx < 16 * 64; idx += 256) {
        int y = idx & 15, q = idx >> 4;
        int gq2 = q0 + q;
        ry_s[y][q] = (gq2 < NQ)
            ? RY[(size_t)(b * NQ + gq2) * (NHEAD * GRID) + h * GRID + sp * 16 + y] : 0.f;
    }

    short8 qf = *(const short8*)(Qbf + ((size_t)(b * NQ + gq)) * DIMM + h * HD + 8 * g);

    const int sr = tid >> 2, sc = tid & 3;
    const int vd = tid >> 3, vc = tid & 7;
    const size_t kbase = ((size_t)(b * NKV + kv0g + sr)) * DIMM + h * HD + 8 * sc;
    const size_t vbase = ((size_t)((b * NHEAD + h) * HD + vd)) * NKV + kv0g + 8 * vc;

    kbuf[0][sr >> 4][(sr & 15) + 16 * sc] = *(const short8*)(Kbf + kbase);
    vbuf[0][(vc >> 2) * 2 + (vd >> 4)][16 * (vc & 3) + (vd & 15)] = *(const short8*)(Vt + vbase);
    if (tid < 64) mbuf[0][tid] = -100.f * (float)mask[b * NKV + kv0g + tid];
    __syncthreads();

    f32x4 cacc0 = {0.f, 0.f, 0.f, 0.f};
    f32x4 cacc1 = {0.f, 0.f, 0.f, 0.f};
    float m_run = -1e30f, l_run = 0.f;
    int cur = 0;

    for (int t = 0; t < NT; ++t) {
        short8 rk = {}, rv = {};
        float rm = 0.f;
        if (t < NT - 1) {
            size_t kvn = (size_t)(t + 1) * 64;
            rk = *(const short8*)(Kbf + kbase + kvn * DIMM);
            rv = *(const short8*)(Vt + vbase + kvn);
            if (tid < 64) rm = -100.f * (float)mask[b * NKV + kv0g + kvn + tid];
        }

        f32x4 zero = {0.f, 0.f, 0.f, 0.f};
        f32x4 s[4];
        __builtin_amdgcn_s_setprio(1);
        #pragma unroll
        for (int kt = 0; kt < 4; ++kt)
            s[kt] = __builtin_amdgcn_mfma_f32_16x16x32_bf16(kbuf[cur][kt][lane], qf, zero, 0, 0, 0);
        __builtin_amdgcn_s_setprio(0);

        float ryb = ry_s[t][wq];
        #pragma unroll
        for (int kt = 0; kt < 4; ++kt) {
            #pragma unroll
            for (int r = 0; r < 4; ++r)
                s[kt][r] += rxr[kt * 4 + r] + ryb + mbuf[cur][16 * kt + 4 * g + r];
        }

        float mloc = s[0][0];
        #pragma unroll
        for (int kt = 0; kt < 4; ++kt)
            #pragma unroll
            for (int r = 0; r < 4; ++r) mloc = fmaxf(mloc, s[kt][r]);
        mloc = fmaxf(mloc, __shfl_xor(mloc, 16));
        mloc = fmaxf(mloc, __shfl_xor(mloc, 32));
        float mnew = fmaxf(m_run, mloc);
        float fsc  = __expf(m_run - mnew);
        float psum = 0.f;
        #pragma unroll
        for (int kt = 0; kt < 4; ++kt)
            #pragma unroll
            for (int r = 0; r < 4; ++r) {
                float pv = __expf(s[kt][r] - mnew);
                s[kt][r] = pv;
                psum += pv;
            }
        psum += __shfl_xor(psum, 16);
        psum += __shfl_xor(psum, 32);
        l_run = l_run * fsc + psum;
        m_run = mnew;
        cacc0 *= fsc;
        cacc1 *= fsc;

        #pragma unroll
        for (int kt = 0; kt < 4; ++kt) {
            unsigned d0 = packbf2(s[kt][0], s[kt][1]);
            unsigned d1 = packbf2(s[kt][2], s[kt][3]);
            int lt = 16 * ((2 * kt + (g >> 1)) & 3) + q15;
            uint2v* dst = (uint2v*)&pbuf[w][kt >> 1][lt][2 * (g & 1)];
            *dst = (uint2v){d0, d1};
        }

        __builtin_amdgcn_s_setprio(1);
        #pragma unroll
        for (int sk = 0; sk < 2; ++sk) {
            short8 pf = *(const short8*)&pbuf[w][sk][lane][0];
            cacc0 = __builtin_amdgcn_mfma_f32_16x16x32_bf16(vbuf[cur][sk * 2 + 0][lane], pf, cacc0, 0, 0, 0);
            cacc1 = __builtin_amdgcn_mfma_f32_16x16x32_bf16(vbuf[cur][sk * 2 + 1][lane], pf, cacc1, 0, 0, 0);
        }
        __builtin_amdgcn_s_setprio(0);

        if (t < NT - 1) {
            kbuf[cur ^ 1][sr >> 4][(sr & 15) + 16 * sc] = rk;
            vbuf[cur ^ 1][(vc >> 2) * 2 + (vd >> 4)][16 * (vc & 3) + (vd & 15)] = rv;
            if (tid < 64) mbuf[cur ^ 1][tid] = rm;
        }
        __syncthreads();
        cur ^= 1;
    }

    size_t prow = (size_t)(sp * NB + b) * NQP + gq;
    float* pc = pctx + prow * DIMM + h * HD;
    #pragma unroll
    for (int r = 0; r < 4; ++r) {
        pc[4 * g + r]      = cacc0[r];
        pc[16 + 4 * g + r] = cacc1[r];
    }
    if (g == 0) {
        float2 v; v.x = m_run; v.y = l_run;
        pml[prow * NHEAD + h] = v;
    }
}

// ---------------------------------------------------------------------------
// Combine the 4 KV-split partials (unchanged, verified).
// ---------------------------------------------------------------------------
__global__ __launch_bounds__(256) void attn_reduce(
    const float* __restrict__ pctx, const float2* __restrict__ pml,
    float* __restrict__ CTX)
{
    const int bq = blockIdx.x;
    const int b = bq / NQ, q = bq - b * NQ;
    const int c = threadIdx.x;
    const int h = c >> 5;

    float m[SPLIT], l[SPLIT];
    #pragma unroll
    for (int sp = 0; sp < SPLIT; ++sp) {
        float2 v = pml[((size_t)(sp * NB + b) * NQP + q) * NHEAD + h];
        m[sp] = v.x; l[sp] = v.y;
    }
    float ms = fmaxf(fmaxf(m[0], m[1]), fmaxf(m[2], m[3]));
    float L = 0.f, acc = 0.f;
    #pragma unroll
    for (int sp = 0; sp < SPLIT; ++sp) {
        float wgt = __expf(m[sp] - ms);
        L   += wgt * l[sp];
        acc += wgt * pctx[((size_t)(sp * NB + b) * NQP + q) * DIMM + c];
    }
    CTX[(size_t)bq * DIMM + c] = acc / L;
}

// ---------------------------------------------------------------------------
// fp32 GEMM for the output projection (unchanged, verified).
// ---------------------------------------------------------------------------
__global__ __launch_bounds__(256) void gemm_bias_f32(
    const float* __restrict__ A, const float* __restrict__ W,
    const float* __restrict__ bias, float* __restrict__ C,
    int M, int N, int K)
{
    __shared__ float As[32][33];
    __shared__ float Ws[32][33];
    const int t  = threadIdx.x;
    const int tr = t >> 4;
    const int tc = t & 15;
    const int brow = blockIdx.y * 32;
    const int bcol = blockIdx.x * 32;
    float acc00 = 0.f, acc01 = 0.f, acc10 = 0.f, acc11 = 0.f;

    for (int kt = 0; kt < K; kt += 32) {
        #pragma unroll
        for (int i = 0; i < 4; ++i) {
            int idx = t + i * 256;
            int r = idx >> 5, c = idx & 31;
            int gr = brow + r;
            As[r][c] = (gr < M) ? A[(size_t)gr * K + kt + c] : 0.f;
            Ws[r][c] = W[(size_t)(bcol + r) * K + kt + c];
        }
        __syncthreads();
        #pragma unroll 8
        for (int k = 0; k < 32; ++k) {
            float a0 = As[tr * 2][k], a1 = As[tr * 2 + 1][k];
            float w0 = Ws[tc * 2][k], w1 = Ws[tc * 2 + 1][k];
            acc00 += a0 * w0; acc01 += a0 * w1;
            acc10 += a1 * w0; acc11 += a1 * w1;
        }
        __syncthreads();
    }
    int gc0 = bcol + tc * 2, gc1 = gc0 + 1;
    int gr0 = brow + tr * 2, gr1 = gr0 + 1;
    if (gr0 < M) {
        C[(size_t)gr0 * N + gc0] = acc00 + bias[gc0];
        C[(size_t)gr0 * N + gc1] = acc01 + bias[gc1];
    }
    if (gr1 < M) {
        C[(size_t)gr1 * N + gc0] = acc10 + bias[gc0];
        C[(size_t)gr1 * N + gc1] = acc11 + bias[gc1];
    }
}

// ---------------------------------------------------------------------------
extern "C" void kernel_launch(void* const* d_in, const int* in_sizes, int n_in,
                              void* d_out, int out_size, void* d_ws, size_t ws_size,
                              hipStream_t stream)
{
    const float* hs   = (const float*)d_in[0];
    const float* rp   = (const float*)d_in[1];
    const float* kv   = (const float*)d_in[2];
    const int*   msk  = (const int*)d_in[4];
    const float* m1w1 = (const float*)d_in[5];
    const float* m1b1 = (const float*)d_in[6];
    const float* m1w2 = (const float*)d_in[7];
    const float* m2w1 = (const float*)d_in[8];
    const float* m2b1 = (const float*)d_in[9];
    const float* m2w2 = (const float*)d_in[10];
    const float* q_w  = (const float*)d_in[11];
    const float* q_b  = (const float*)d_in[12];
    const float* k_w  = (const float*)d_in[13];
    const float* k_b  = (const float*)d_in[14];
    const float* v_w  = (const float*)d_in[15];
    const float* v_b  = (const float*)d_in[16];
    const float* o_w  = (const float*)d_in[17];
    const float* o_b  = (const float*)d_in[18];
    float* out = (float*)d_out;

    char* p = (char*)d_ws;
    float* RX   = (float*)p; p += (size_t)NB * NQ * NHEAD * GRID * 4;
    float* RY   = (float*)p; p += (size_t)NB * NQ * NHEAD * GRID * 4;
    float* CTX  = (float*)p; p += (size_t)NB * NQ * DIMM * 4;
    u16*   Qbf  = (u16*)p;   p += (size_t)1920 * DIMM * 2;
    u16*   Kbf  = (u16*)p;   p += (size_t)NB * NKV * DIMM * 2;
    u16*   Vt   = (u16*)p;   p += (size_t)NB * NHEAD * HD * NKV * 2;

    // union region: {bf16 conv buffers} (conv..proj) / {attn partials} (attn..reduce)
    char* u = p;
    u16* hsbf = (u16*)u;
    u16* kvbf = hsbf + (size_t)1920 * DIMM;
    u16* qwbf = kvbf + (size_t)NB * NKV * DIMM;
    u16* kwbf = qwbf + (size_t)DIMM * DIMM;
    u16* vwbf = kwbf + (size_t)DIMM * DIMM;
    float*  pctx = (float*)u;
    float2* pml  = (float2*)(pctx + (size_t)SPLIT * NB * NQP * DIMM);

    const float scale = 0.17677669529663687f;  // 32^-0.5

    // 1) fp32 -> bf16 conversion
    conv_bf16<<<1024, 256, 0, stream>>>(hs, kv, q_w, k_w, v_w,
                                        hsbf, kvbf, qwbf, kwbf, vwbf);

    // 2) Q projection (bf16 MFMA, scale folded)
    proj_mfma<<<dim3(15, 2, 1), 256, 0, stream>>>(
        hsbf, qwbf, q_b, nullptr, nullptr, Qbf, nullptr, NB * NQ, scale);

    // 3) K + V projections fused (z=0 -> K row-major, z=1 -> V transposed)
    proj_mfma<<<dim3(64, 2, 2), 256, 0, stream>>>(
        kvbf, kwbf, k_b, vwbf, v_b, Kbf, Vt, NB * NKV, 1.f);

    // 4) RPE MLPs (900 blocks x 256 threads; r-split x G=2, 3600 waves)
    rpe_kernel<<<900, 256, 0, stream>>>(rp, m1w1, m1b1, m1w2,
                                        m2w1, m2b1, m2w2, RX, RY);

    // 5) MFMA attention, KV-split x4
    attn_mfma<<<dim3((NQ + 63) / 64, NHEAD, NB * SPLIT), 256, 0, stream>>>(
        Qbf, Kbf, Vt, RX, RY, msk, pctx, pml);

    // 6) combine partials
    attn_reduce<<<NB * NQ, 256, 0, stream>>>(pctx, pml, CTX);

    // 7) Output projection (fp32)
    gemm_bias_f32<<<dim3(DIMM / 32, (NB * NQ + 31) / 32), 256, 0, stream>>>(
        CTX, o_w, o_b, out, NB * NQ, DIMM, DIMM);
}